// Round 1
// baseline (670.437 us; speedup 1.0000x reference)
//
#include <hip/hip_runtime.h>
#include <hip/hip_bf16.h>
#include <stdint.h>

#define N_TOK 16384
#define DMODEL 1024
#define EXP 16
#define CAP 4096
#define TT 32768          // N_TOK * K (K=2)

typedef __bf16 bf16x8 __attribute__((ext_vector_type(8)));
typedef float  f32x4  __attribute__((ext_vector_type(4)));

__device__ __forceinline__ void gl_lds16(const void* g, void* s) {
  __builtin_amdgcn_global_load_lds(
      (__attribute__((address_space(1))) void*)(void*)g,
      (__attribute__((address_space(3))) void*)s, 16, 0, 0);
}

__device__ __forceinline__ float bfbits2f(unsigned short u) {
  return __uint_as_float(((unsigned)u) << 16);
}

// ---------------- convert X to bf16 (same layout) ----------------
__global__ __launch_bounds__(256) void convx_kernel(const float* __restrict__ in,
                                                    __bf16* __restrict__ o) {
  size_t i = ((size_t)blockIdx.x * 256 + threadIdx.x) * 8;
  float4 a = *(const float4*)(in + i);
  float4 b = *(const float4*)(in + i + 4);
  bf16x8 v;
  v[0] = (__bf16)a.x; v[1] = (__bf16)a.y; v[2] = (__bf16)a.z; v[3] = (__bf16)a.w;
  v[4] = (__bf16)b.x; v[5] = (__bf16)b.y; v[6] = (__bf16)b.z; v[7] = (__bf16)b.w;
  *(bf16x8*)(o + i) = v;
}

// ------------- transpose + convert W1/W2 to bf16 [e][n][k] -------------
__global__ __launch_bounds__(256) void convw_kernel(const float* __restrict__ W1,
                                                    const float* __restrict__ W2,
                                                    __bf16* __restrict__ W1bt,
                                                    __bf16* __restrict__ W2bt) {
  __shared__ float tile[64][65];
  int b = blockIdx.x;
  int tx = b & 15;           // col-tile (k dim of source)
  int ty = (b >> 4) & 15;    // row-tile
  int e  = (b >> 8) & 15;
  int which = (b >> 12) & 1;
  const float* src = (which ? W2 : W1) + (size_t)e * DMODEL * DMODEL;
  __bf16*      dst = (which ? W2bt : W1bt) + (size_t)e * DMODEL * DMODEL;
  int t = threadIdx.x;
  int r = t >> 2;             // 0..63
  int cs = (t & 3) * 16;      // 0,16,32,48
  int r0 = ty * 64, c0 = tx * 64;
  #pragma unroll
  for (int i = 0; i < 16; i += 4) {
    float4 v = *(const float4*)(src + (size_t)(r0 + r) * DMODEL + c0 + cs + i);
    tile[r][cs + i + 0] = v.x; tile[r][cs + i + 1] = v.y;
    tile[r][cs + i + 2] = v.z; tile[r][cs + i + 3] = v.w;
  }
  __syncthreads();
  bf16x8 o1, o2;
  #pragma unroll
  for (int i = 0; i < 8; i++) o1[i] = (__bf16)tile[cs + i][r];
  #pragma unroll
  for (int i = 0; i < 8; i++) o2[i] = (__bf16)tile[cs + 8 + i][r];
  *(bf16x8*)(dst + (size_t)(c0 + r) * DMODEL + r0 + cs)     = o1;
  *(bf16x8*)(dst + (size_t)(c0 + r) * DMODEL + r0 + cs + 8) = o2;
}

// ---------------- gate: logits, top-2 per half, route select ----------------
__global__ __launch_bounds__(256) void gate_kernel(const float* __restrict__ x,
                                                   const float* __restrict__ gw,
                                                   const float* __restrict__ gb,
                                                   const float* __restrict__ rw,
                                                   const float* __restrict__ rb,
                                                   int* __restrict__ idxo,
                                                   float* __restrict__ sco) {
  int w = threadIdx.x >> 6, lane = threadIdx.x & 63;
  int n = blockIdx.x * 4 + w;
  const float* xr = x + (size_t)n * DMODEL;
  float acc[17];
  #pragma unroll
  for (int j = 0; j < 17; j++) acc[j] = 0.f;
  for (int d = lane; d < DMODEL; d += 64) {
    float xv = xr[d];
    #pragma unroll
    for (int j = 0; j < 16; j++) acc[j] += xv * gw[d * 16 + j];
    acc[16] += xv * rw[d];
  }
  #pragma unroll
  for (int o = 1; o < 64; o <<= 1) {
    #pragma unroll
    for (int j = 0; j < 17; j++) acc[j] += __shfl_xor(acc[j], o);
  }
  if (lane == 0) {
    float rv = acc[16] + rb[0];
    bool g1 = rv > 0.f;
    float c[8];
    #pragma unroll
    for (int j = 0; j < 8; j++)
      c[j] = (g1 ? acc[j] + gb[j] : acc[8 + j] + gb[8 + j]);
    int i1 = 0; float v1 = c[0];
    #pragma unroll
    for (int j = 1; j < 8; j++) { if (c[j] > v1) { v1 = c[j]; i1 = j; } }
    int i2 = -1; float v2 = -3.4e38f;
    #pragma unroll
    for (int j = 0; j < 8; j++) { if (j != i1 && c[j] > v2) { v2 = c[j]; i2 = j; } }
    float e2 = expf(v2 - v1);
    float den = 1.f + e2;
    int base = g1 ? 0 : 8;
    idxo[2 * n] = base + i1; idxo[2 * n + 1] = base + i2;
    sco[2 * n] = 1.f / den;  sco[2 * n + 1] = e2 / den;
  }
}

// ------------- scan: t-ordered per-expert ranks, rowlists, offsets -------------
__global__ __launch_bounds__(1024) void scan_kernel(const int* __restrict__ idx,
                                                    float* __restrict__ sco,
                                                    int* __restrict__ rowlist,
                                                    int* __restrict__ cnt,
                                                    int* __restrict__ off) {
  __shared__ int hist[16 * 1024];   // 64 KB
  int tid = threadIdx.x;
  #pragma unroll
  for (int e = 0; e < 16; e++) hist[e * 1024 + tid] = 0;
  __syncthreads();
  int base = tid * 32;
  for (int i = 0; i < 32; i++) {
    int e = idx[base + i];
    hist[e * 1024 + tid]++;
  }
  __syncthreads();
  int w = tid >> 6, lane = tid & 63;
  {
    int e = w;  // 16 waves == 16 experts
    int running = 0;
    for (int cch = 0; cch < 16; cch++) {
      int v = hist[e * 1024 + cch * 64 + lane];
      int orig = v;
      #pragma unroll
      for (int o = 1; o < 64; o <<= 1) {
        int nv = __shfl_up(v, o);
        if (lane >= o) v += nv;
      }
      hist[e * 1024 + cch * 64 + lane] = running + v - orig;  // exclusive base
      running += __shfl(v, 63);
    }
    if (lane == 0) cnt[e] = running;   // raw count
  }
  __syncthreads();
  if (tid == 0) {
    int o = 0;
    for (int e = 0; e < 16; e++) {
      int c = cnt[e]; if (c > CAP) c = CAP;
      off[e] = o; cnt[e] = c; o += c;
    }
  }
  __syncthreads();
  for (int i = 0; i < 32; i++) {
    int t = base + i;
    int e = idx[t];
    int r = hist[e * 1024 + tid]++;
    if (r < CAP) rowlist[e * CAP + r] = t;
    else sco[t] = 0.f;   // dropped slot contributes zero
  }
}

// ---------------- grouped GEMM (m97-style 128x128x64, bf16 MFMA) ----------------
#define BM 128
#define BN 128
#define BK 64

__global__ __launch_bounds__(256) void moe_gemm(const __bf16* __restrict__ A,
                                                const __bf16* __restrict__ Bt,
                                                const float* __restrict__ bias,
                                                __bf16* __restrict__ out,
                                                const int* __restrict__ rowlist,
                                                const int* __restrict__ cnt,
                                                const int* __restrict__ off,
                                                int mode) {
  __shared__ __bf16 As[BM][BK];
  __shared__ __bf16 Bs[BN][BK];
  int e  = blockIdx.x >> 5;
  int m0 = (blockIdx.x & 31) * BM;
  int ce = cnt[e];
  if (m0 >= ce) return;
  int n0 = blockIdx.y * BN;
  int oe = off[e];
  int tid = threadIdx.x;

  const __bf16* aP[4];
  const __bf16* bP[4];
  #pragma unroll
  for (int i = 0; i < 4; i++) {
    int lin = i * 256 + tid;
    int r = lin >> 3;
    int cs = (lin & 7) * 8;
    int rr = m0 + r; if (rr > ce - 1) rr = ce - 1;
    size_t arow;
    if (mode == 0) arow = (size_t)(rowlist[e * CAP + rr] >> 1);  // token id
    else           arow = (size_t)(oe + rr);                     // h row
    aP[i] = A + arow * DMODEL + cs;
    bP[i] = Bt + (size_t)e * DMODEL * DMODEL + (size_t)(n0 + r) * DMODEL + cs;
  }

  int w = tid >> 6, lane = tid & 63;
  int wr = (w >> 1) * 64, wc = (w & 1) * 64;
  int fr = lane & 15, fg = lane >> 4;

  f32x4 acc[4][4];
  #pragma unroll
  for (int mi = 0; mi < 4; mi++)
    #pragma unroll
    for (int ni = 0; ni < 4; ni++)
      #pragma unroll
      for (int l = 0; l < 4; l++) acc[mi][ni][l] = 0.f;

  for (int k0 = 0; k0 < DMODEL; k0 += BK) {
    #pragma unroll
    for (int i = 0; i < 4; i++) {
      gl_lds16(aP[i] + k0, (char*)(&As[0][0]) + (size_t)(i * 256 + tid) * 16);
      gl_lds16(bP[i] + k0, (char*)(&Bs[0][0]) + (size_t)(i * 256 + tid) * 16);
    }
    __syncthreads();
    #pragma unroll
    for (int kk = 0; kk < 2; kk++) {
      bf16x8 af[4], bfr[4];
      #pragma unroll
      for (int mi = 0; mi < 4; mi++)
        af[mi] = *(const bf16x8*)&As[wr + mi * 16 + fr][kk * 32 + fg * 8];
      #pragma unroll
      for (int ni = 0; ni < 4; ni++)
        bfr[ni] = *(const bf16x8*)&Bs[wc + ni * 16 + fr][kk * 32 + fg * 8];
      #pragma unroll
      for (int mi = 0; mi < 4; mi++)
        #pragma unroll
        for (int ni = 0; ni < 4; ni++)
          acc[mi][ni] = __builtin_amdgcn_mfma_f32_16x16x32_bf16(af[mi], bfr[ni], acc[mi][ni], 0, 0, 0);
    }
    __syncthreads();
  }

  float bcol[4];
  #pragma unroll
  for (int ni = 0; ni < 4; ni++)
    bcol[ni] = bias[(size_t)e * DMODEL + n0 + wc + ni * 16 + fr];
  #pragma unroll
  for (int mi = 0; mi < 4; mi++) {
    #pragma unroll
    for (int r = 0; r < 4; r++) {
      int grow = m0 + wr + mi * 16 + fg * 4 + r;
      if (grow >= ce) continue;
      size_t orow = (mode == 0) ? (size_t)(oe + grow)
                                : (size_t)rowlist[e * CAP + grow];
      __bf16* op = out + orow * DMODEL + n0 + wc + fr;
      #pragma unroll
      for (int ni = 0; ni < 4; ni++) {
        float v = acc[mi][ni][r] + bcol[ni];
        if (mode == 0) v = fmaxf(v, 0.f);
        op[ni * 16] = (__bf16)v;
      }
    }
  }
}

// ---------------- combine: out[n] = s0*y[2n] + s1*y[2n+1] ----------------
__global__ __launch_bounds__(256) void combine_kernel(const __bf16* __restrict__ y,
                                                      const float* __restrict__ sco,
                                                      float* __restrict__ out) {
  int n = blockIdx.x;
  int d = threadIdx.x * 4;
  float s0 = sco[2 * n], s1 = sco[2 * n + 1];
  ushort4 a = *(const ushort4*)((const unsigned short*)(y + (size_t)(2 * n) * DMODEL + d));
  ushort4 b = *(const ushort4*)((const unsigned short*)(y + (size_t)(2 * n + 1) * DMODEL + d));
  float4 o;
  o.x = s0 * bfbits2f(a.x) + s1 * bfbits2f(b.x);
  o.y = s0 * bfbits2f(a.y) + s1 * bfbits2f(b.y);
  o.z = s0 * bfbits2f(a.z) + s1 * bfbits2f(b.z);
  o.w = s0 * bfbits2f(a.w) + s1 * bfbits2f(b.w);
  *(float4*)(out + (size_t)n * DMODEL + d) = o;
}

extern "C" void kernel_launch(void* const* d_in, const int* in_sizes, int n_in,
                              void* d_out, int out_size, void* d_ws, size_t ws_size,
                              hipStream_t stream) {
  const float* moe = (const float*)d_in[0];
  const float* gw  = (const float*)d_in[1];
  const float* gb  = (const float*)d_in[2];
  const float* rw  = (const float*)d_in[3];
  const float* rb  = (const float*)d_in[4];
  const float* W1  = (const float*)d_in[5];
  const float* b1  = (const float*)d_in[6];
  const float* W2  = (const float*)d_in[7];
  const float* b2  = (const float*)d_in[8];
  float* out = (float*)d_out;

  char* p = (char*)d_ws;
  __bf16* Xb   = (__bf16*)p; p += (size_t)N_TOK * DMODEL * 2;
  __bf16* W1bt = (__bf16*)p; p += (size_t)EXP * DMODEL * DMODEL * 2;
  __bf16* W2bt = (__bf16*)p; p += (size_t)EXP * DMODEL * DMODEL * 2;
  __bf16* hbuf = (__bf16*)p; p += (size_t)TT * DMODEL * 2;
  __bf16* ybuf = (__bf16*)p; p += (size_t)TT * DMODEL * 2;
  int*   idxb   = (int*)p;   p += (size_t)TT * 4;
  float* scoreb = (float*)p; p += (size_t)TT * 4;
  int*   rowlist = (int*)p;  p += (size_t)EXP * CAP * 4;
  int*   cntb    = (int*)p;  p += 64;
  int*   offb    = (int*)p;  p += 64;

  convx_kernel<<<dim3(8192), dim3(256), 0, stream>>>(moe, Xb);
  convw_kernel<<<dim3(8192), dim3(256), 0, stream>>>(W1, W2, W1bt, W2bt);
  gate_kernel<<<dim3(4096), dim3(256), 0, stream>>>(moe, gw, gb, rw, rb, idxb, scoreb);
  scan_kernel<<<dim3(1), dim3(1024), 0, stream>>>(idxb, scoreb, rowlist, cntb, offb);
  moe_gemm<<<dim3(512, 8), dim3(256), 0, stream>>>(Xb, W1bt, b1, hbuf, rowlist, cntb, offb, 0);
  moe_gemm<<<dim3(512, 8), dim3(256), 0, stream>>>(hbuf, W2bt, b2, ybuf, rowlist, cntb, offb, 1);
  combine_kernel<<<dim3(16384), dim3(256), 0, stream>>>(ybuf, scoreb, out);
}

// Round 2
// 509.425 us; speedup vs baseline: 1.3161x; 1.3161x over previous
//
#include <hip/hip_runtime.h>
#include <hip/hip_bf16.h>
#include <stdint.h>

#define N_TOK 16384
#define DMODEL 1024
#define EXP 16
#define CAP 4096
#define TT 32768          // N_TOK * K (K=2)

typedef __bf16 bf16x8 __attribute__((ext_vector_type(8)));
typedef __bf16 bf16x4 __attribute__((ext_vector_type(4)));
typedef float  f32x4  __attribute__((ext_vector_type(4)));

__device__ __forceinline__ void gl_lds16(const void* g, void* s) {
  __builtin_amdgcn_global_load_lds(
      (__attribute__((address_space(1))) void*)(void*)g,
      (__attribute__((address_space(3))) void*)s, 16, 0, 0);
}

__device__ __forceinline__ float bfbits2f(unsigned short u) {
  return __uint_as_float(((unsigned)u) << 16);
}

// ------------- transpose + convert W1/W2 to bf16 [e][n][k] -------------
__global__ __launch_bounds__(256) void convw_kernel(const float* __restrict__ W1,
                                                    const float* __restrict__ W2,
                                                    __bf16* __restrict__ W1bt,
                                                    __bf16* __restrict__ W2bt) {
  __shared__ float tile[64][65];
  int b = blockIdx.x;
  int tx = b & 15;           // col-tile (k dim of source)
  int ty = (b >> 4) & 15;    // row-tile
  int e  = (b >> 8) & 15;
  int which = (b >> 12) & 1;
  const float* src = (which ? W2 : W1) + (size_t)e * DMODEL * DMODEL;
  __bf16*      dst = (which ? W2bt : W1bt) + (size_t)e * DMODEL * DMODEL;
  int t = threadIdx.x;
  int r = t >> 2;             // 0..63
  int cs = (t & 3) * 16;      // 0,16,32,48
  int r0 = ty * 64, c0 = tx * 64;
  #pragma unroll
  for (int i = 0; i < 16; i += 4) {
    float4 v = *(const float4*)(src + (size_t)(r0 + r) * DMODEL + c0 + cs + i);
    tile[r][cs + i + 0] = v.x; tile[r][cs + i + 1] = v.y;
    tile[r][cs + i + 2] = v.z; tile[r][cs + i + 3] = v.w;
  }
  __syncthreads();
  bf16x8 o1, o2;
  #pragma unroll
  for (int i = 0; i < 8; i++) o1[i] = (__bf16)tile[cs + i][r];
  #pragma unroll
  for (int i = 0; i < 8; i++) o2[i] = (__bf16)tile[cs + 8 + i][r];
  *(bf16x8*)(dst + (size_t)(c0 + r) * DMODEL + r0 + cs)     = o1;
  *(bf16x8*)(dst + (size_t)(c0 + r) * DMODEL + r0 + cs + 8) = o2;
}

// ------- gate: logits, top-2 per half, route select; fused X->bf16 -------
__global__ __launch_bounds__(256) void gate_kernel(const float* __restrict__ x,
                                                   const float* __restrict__ gw,
                                                   const float* __restrict__ gb,
                                                   const float* __restrict__ rw,
                                                   const float* __restrict__ rb,
                                                   int* __restrict__ idxo,
                                                   float* __restrict__ sco,
                                                   __bf16* __restrict__ Xb) {
  int w = threadIdx.x >> 6, lane = threadIdx.x & 63;
  int n = blockIdx.x * 4 + w;
  const float* xr = x + (size_t)n * DMODEL;
  float acc[17];
  #pragma unroll
  for (int j = 0; j < 17; j++) acc[j] = 0.f;
  #pragma unroll
  for (int it = 0; it < 4; it++) {
    int d = it * 256 + lane * 4;
    float4 v = *(const float4*)(xr + d);
    bf16x4 bv;
    bv[0] = (__bf16)v.x; bv[1] = (__bf16)v.y; bv[2] = (__bf16)v.z; bv[3] = (__bf16)v.w;
    *(bf16x4*)(Xb + (size_t)n * DMODEL + d) = bv;
    float xs[4] = {v.x, v.y, v.z, v.w};
    #pragma unroll
    for (int u = 0; u < 4; u++) {
      #pragma unroll
      for (int j = 0; j < 16; j++) acc[j] += xs[u] * gw[(d + u) * 16 + j];
      acc[16] += xs[u] * rw[d + u];
    }
  }
  #pragma unroll
  for (int o = 1; o < 64; o <<= 1) {
    #pragma unroll
    for (int j = 0; j < 17; j++) acc[j] += __shfl_xor(acc[j], o);
  }
  if (lane == 0) {
    float rv = acc[16] + rb[0];
    bool g1 = rv > 0.f;
    float c[8];
    #pragma unroll
    for (int j = 0; j < 8; j++)
      c[j] = (g1 ? acc[j] + gb[j] : acc[8 + j] + gb[8 + j]);
    int i1 = 0; float v1 = c[0];
    #pragma unroll
    for (int j = 1; j < 8; j++) { if (c[j] > v1) { v1 = c[j]; i1 = j; } }
    int i2 = -1; float v2 = -3.4e38f;
    #pragma unroll
    for (int j = 0; j < 8; j++) { if (j != i1 && c[j] > v2) { v2 = c[j]; i2 = j; } }
    float e2 = expf(v2 - v1);
    float den = 1.f + e2;
    int base = g1 ? 0 : 8;
    idxo[2 * n] = base + i1; idxo[2 * n + 1] = base + i2;
    sco[2 * n] = 1.f / den;  sco[2 * n + 1] = e2 / den;
  }
}

// ------------- scan: t-ordered per-expert ranks, rowlists, offsets -------------
__global__ __launch_bounds__(1024) void scan_kernel(const int* __restrict__ idx,
                                                    float* __restrict__ sco,
                                                    int* __restrict__ rowlist,
                                                    int* __restrict__ cnt,
                                                    int* __restrict__ off) {
  __shared__ int hist[16 * 1024];   // 64 KB
  int tid = threadIdx.x;
  #pragma unroll
  for (int e = 0; e < 16; e++) hist[e * 1024 + tid] = 0;
  __syncthreads();
  int base = tid * 32;
  for (int i = 0; i < 32; i++) {
    int e = idx[base + i];
    hist[e * 1024 + tid]++;
  }
  __syncthreads();
  int w = tid >> 6, lane = tid & 63;
  {
    int e = w;  // 16 waves == 16 experts
    int running = 0;
    for (int cch = 0; cch < 16; cch++) {
      int v = hist[e * 1024 + cch * 64 + lane];
      int orig = v;
      #pragma unroll
      for (int o = 1; o < 64; o <<= 1) {
        int nv = __shfl_up(v, o);
        if (lane >= o) v += nv;
      }
      hist[e * 1024 + cch * 64 + lane] = running + v - orig;  // exclusive base
      running += __shfl(v, 63);
    }
    if (lane == 0) cnt[e] = running;   // raw count
  }
  __syncthreads();
  if (tid == 0) {
    int o = 0;
    for (int e = 0; e < 16; e++) {
      int c = cnt[e]; if (c > CAP) c = CAP;
      off[e] = o; cnt[e] = c; o += c;
    }
  }
  __syncthreads();
  for (int i = 0; i < 32; i++) {
    int t = base + i;
    int e = idx[t];
    int r = hist[e * 1024 + tid]++;
    if (r < CAP) rowlist[e * CAP + r] = t;
    else sco[t] = 0.f;   // dropped slot contributes zero
  }
}

// ------- grouped GEMM: 256x256x64 tile, 8 waves, prefetch double-buffer -------
#define GBM 256
#define GBN 256
#define GBK 64
#define NKT (DMODEL / GBK)   // 16 K-steps

__global__ __launch_bounds__(512) void moe_gemm(const __bf16* __restrict__ A,
                                                const __bf16* __restrict__ Bt,
                                                const float* __restrict__ bias,
                                                __bf16* __restrict__ out,
                                                const int* __restrict__ rowlist,
                                                const int* __restrict__ cnt,
                                                const int* __restrict__ off,
                                                int mode) {
  __shared__ char lds[131072];   // A: 2 x 32KB, B: 2 x 32KB
  // XCD-aware bijective swizzle on (expert, mtile): nwg=256, 256%8==0
  int bx = blockIdx.x;
  int em = (bx & 7) * 32 + (bx >> 3);
  int e  = em >> 4;
  int m0 = (em & 15) * GBM;
  int ce = cnt[e];
  if (m0 >= ce) return;
  int n0 = blockIdx.y * GBN;
  int oe = off[e];
  int tid = threadIdx.x;

  // staging source pointers: 4 A-granules + 4 B-granules (16B each) per thread
  const __bf16* aP[4];
  const __bf16* bP[4];
  #pragma unroll
  for (int j = 0; j < 4; j++) {
    int lin = j * 512 + tid;
    int r = lin >> 3;          // 0..255
    int g = lin & 7;           // 16B granule within 64-col row
    int rr = m0 + r; if (rr > ce - 1) rr = ce - 1;
    size_t arow;
    if (mode == 0) arow = (size_t)(rowlist[e * CAP + rr] >> 1);  // token id
    else           arow = (size_t)(oe + rr);                     // h row
    aP[j] = A + arow * DMODEL + g * 8;
    bP[j] = Bt + (size_t)e * DMODEL * DMODEL + (size_t)(n0 + r) * DMODEL + g * 8;
  }

  int w = tid >> 6, lane = tid & 63;
  int wr = (w >> 2) * 128;   // wave row: 2 M-groups of 128
  int wc = (w & 3) * 64;     // wave col: 4 N-groups of 64
  int fr = lane & 15, fg = lane >> 4;

  f32x4 acc[8][4];
  #pragma unroll
  for (int mi = 0; mi < 8; mi++)
    #pragma unroll
    for (int ni = 0; ni < 4; ni++)
      #pragma unroll
      for (int l = 0; l < 4; l++) acc[mi][ni][l] = 0.f;

  // prologue: stage tile 0 into buffer 0
  #pragma unroll
  for (int j = 0; j < 4; j++) {
    gl_lds16(aP[j], lds + (size_t)(j * 512 + tid) * 16);
    gl_lds16(bP[j], lds + 65536 + (size_t)(j * 512 + tid) * 16);
  }
  __syncthreads();

  int cur = 0;
  for (int t = 0; t < NKT; t++) {
    // prefetch next K-tile into the other buffer (overlaps MFMA below)
    if (t < NKT - 1) {
      int k0 = (t + 1) * GBK;
      char* Ad = lds + (cur ^ 1) * 32768;
      char* Bd = lds + 65536 + (cur ^ 1) * 32768;
      #pragma unroll
      for (int j = 0; j < 4; j++) {
        gl_lds16(aP[j] + k0, Ad + (size_t)(j * 512 + tid) * 16);
        gl_lds16(bP[j] + k0, Bd + (size_t)(j * 512 + tid) * 16);
      }
    }
    // compute current buffer
    char* As = lds + cur * 32768;
    char* Bs = lds + 65536 + cur * 32768;
    #pragma unroll
    for (int kk = 0; kk < 2; kk++) {
      bf16x8 af[8], bfr[4];
      #pragma unroll
      for (int mi = 0; mi < 8; mi++)
        af[mi] = *(const bf16x8*)(As + (size_t)(wr + mi * 16 + fr) * 128 + kk * 64 + fg * 16);
      #pragma unroll
      for (int ni = 0; ni < 4; ni++)
        bfr[ni] = *(const bf16x8*)(Bs + (size_t)(wc + ni * 16 + fr) * 128 + kk * 64 + fg * 16);
      #pragma unroll
      for (int mi = 0; mi < 8; mi++)
        #pragma unroll
        for (int ni = 0; ni < 4; ni++)
          acc[mi][ni] = __builtin_amdgcn_mfma_f32_16x16x32_bf16(af[mi], bfr[ni], acc[mi][ni], 0, 0, 0);
    }
    __syncthreads();   // drains this wave's vmcnt (prefetch) + all waves' LDS reads
    cur ^= 1;
  }

  float bcol[4];
  #pragma unroll
  for (int ni = 0; ni < 4; ni++)
    bcol[ni] = bias[(size_t)e * DMODEL + n0 + wc + ni * 16 + fr];
  #pragma unroll
  for (int mi = 0; mi < 8; mi++) {
    #pragma unroll
    for (int r = 0; r < 4; r++) {
      int grow = m0 + wr + mi * 16 + fg * 4 + r;
      if (grow >= ce) continue;
      size_t orow = (mode == 0) ? (size_t)(oe + grow)
                                : (size_t)rowlist[e * CAP + grow];
      __bf16* op = out + orow * DMODEL + n0 + wc + fr;
      #pragma unroll
      for (int ni = 0; ni < 4; ni++) {
        float v = acc[mi][ni][r] + bcol[ni];
        if (mode == 0) v = fmaxf(v, 0.f);
        op[ni * 16] = (__bf16)v;
      }
    }
  }
}

// ---------------- combine: out[n] = s0*y[2n] + s1*y[2n+1] ----------------
__global__ __launch_bounds__(256) void combine_kernel(const __bf16* __restrict__ y,
                                                      const float* __restrict__ sco,
                                                      float* __restrict__ out) {
  int n = blockIdx.x;
  int d = threadIdx.x * 4;
  float s0 = sco[2 * n], s1 = sco[2 * n + 1];
  ushort4 a = *(const ushort4*)((const unsigned short*)(y + (size_t)(2 * n) * DMODEL + d));
  ushort4 b = *(const ushort4*)((const unsigned short*)(y + (size_t)(2 * n + 1) * DMODEL + d));
  float4 o;
  o.x = s0 * bfbits2f(a.x) + s1 * bfbits2f(b.x);
  o.y = s0 * bfbits2f(a.y) + s1 * bfbits2f(b.y);
  o.z = s0 * bfbits2f(a.z) + s1 * bfbits2f(b.z);
  o.w = s0 * bfbits2f(a.w) + s1 * bfbits2f(b.w);
  *(float4*)(out + (size_t)n * DMODEL + d) = o;
}

extern "C" void kernel_launch(void* const* d_in, const int* in_sizes, int n_in,
                              void* d_out, int out_size, void* d_ws, size_t ws_size,
                              hipStream_t stream) {
  const float* moe = (const float*)d_in[0];
  const float* gw  = (const float*)d_in[1];
  const float* gb  = (const float*)d_in[2];
  const float* rw  = (const float*)d_in[3];
  const float* rb  = (const float*)d_in[4];
  const float* W1  = (const float*)d_in[5];
  const float* b1  = (const float*)d_in[6];
  const float* W2  = (const float*)d_in[7];
  const float* b2  = (const float*)d_in[8];
  float* out = (float*)d_out;

  char* p = (char*)d_ws;
  __bf16* Xb   = (__bf16*)p; p += (size_t)N_TOK * DMODEL * 2;
  __bf16* W1bt = (__bf16*)p; p += (size_t)EXP * DMODEL * DMODEL * 2;
  __bf16* W2bt = (__bf16*)p; p += (size_t)EXP * DMODEL * DMODEL * 2;
  __bf16* hbuf = (__bf16*)p; p += (size_t)TT * DMODEL * 2;
  __bf16* ybuf = (__bf16*)p; p += (size_t)TT * DMODEL * 2;
  int*   idxb   = (int*)p;   p += (size_t)TT * 4;
  float* scoreb = (float*)p; p += (size_t)TT * 4;
  int*   rowlist = (int*)p;  p += (size_t)EXP * CAP * 4;
  int*   cntb    = (int*)p;  p += 64;
  int*   offb    = (int*)p;  p += 64;

  convw_kernel<<<dim3(8192), dim3(256), 0, stream>>>(W1, W2, W1bt, W2bt);
  gate_kernel<<<dim3(4096), dim3(256), 0, stream>>>(moe, gw, gb, rw, rb, idxb, scoreb, Xb);
  scan_kernel<<<dim3(1), dim3(1024), 0, stream>>>(idxb, scoreb, rowlist, cntb, offb);
  moe_gemm<<<dim3(256, 4), dim3(512), 0, stream>>>(Xb, W1bt, b1, hbuf, rowlist, cntb, offb, 0);
  moe_gemm<<<dim3(256, 4), dim3(512), 0, stream>>>(hbuf, W2bt, b2, ybuf, rowlist, cntb, offb, 1);
  combine_kernel<<<dim3(16384), dim3(256), 0, stream>>>(ybuf, scoreb, out);
}

// Round 3
// 428.628 us; speedup vs baseline: 1.5641x; 1.1885x over previous
//
#include <hip/hip_runtime.h>
#include <hip/hip_bf16.h>
#include <stdint.h>

#define N_TOK 16384
#define DMODEL 1024
#define EXP 16
#define CAP 4096
#define TT 32768          // N_TOK * K (K=2)

typedef __bf16 bf16x8 __attribute__((ext_vector_type(8)));
typedef __bf16 bf16x4 __attribute__((ext_vector_type(4)));
typedef float  f32x4  __attribute__((ext_vector_type(4)));

__device__ __forceinline__ void gl_lds16(const void* g, void* s) {
  __builtin_amdgcn_global_load_lds(
      (__attribute__((address_space(1))) void*)(void*)g,
      (__attribute__((address_space(3))) void*)s, 16, 0, 0);
}

__device__ __forceinline__ float bfbits2f(unsigned short u) {
  return __uint_as_float(((unsigned)u) << 16);
}

// ------------- transpose + convert W1/W2 to bf16 [e][n][k] -------------
__global__ __launch_bounds__(256) void convw_kernel(const float* __restrict__ W1,
                                                    const float* __restrict__ W2,
                                                    __bf16* __restrict__ W1bt,
                                                    __bf16* __restrict__ W2bt) {
  __shared__ float tile[64][65];
  int b = blockIdx.x;
  int tx = b & 15;           // col-tile (k dim of source)
  int ty = (b >> 4) & 15;    // row-tile
  int e  = (b >> 8) & 15;
  int which = (b >> 12) & 1;
  const float* src = (which ? W2 : W1) + (size_t)e * DMODEL * DMODEL;
  __bf16*      dst = (which ? W2bt : W1bt) + (size_t)e * DMODEL * DMODEL;
  int t = threadIdx.x;
  int r = t >> 2;             // 0..63
  int cs = (t & 3) * 16;      // 0,16,32,48
  int r0 = ty * 64, c0 = tx * 64;
  #pragma unroll
  for (int i = 0; i < 16; i += 4) {
    float4 v = *(const float4*)(src + (size_t)(r0 + r) * DMODEL + c0 + cs + i);
    tile[r][cs + i + 0] = v.x; tile[r][cs + i + 1] = v.y;
    tile[r][cs + i + 2] = v.z; tile[r][cs + i + 3] = v.w;
  }
  __syncthreads();
  bf16x8 o1, o2;
  #pragma unroll
  for (int i = 0; i < 8; i++) o1[i] = (__bf16)tile[cs + i][r];
  #pragma unroll
  for (int i = 0; i < 8; i++) o2[i] = (__bf16)tile[cs + 8 + i][r];
  *(bf16x8*)(dst + (size_t)(c0 + r) * DMODEL + r0 + cs)     = o1;
  *(bf16x8*)(dst + (size_t)(c0 + r) * DMODEL + r0 + cs + 8) = o2;
}

// ------- gate: logits via LDS-staged gw (fp32), fused X->bf16 -------
// block = 256 threads = 4 waves, one token per wave.
// gw staged in 2 chunks of 512 rows, LDS stride 17 dwords (odd -> conflict-free).
__global__ __launch_bounds__(256) void gate_kernel(const float* __restrict__ x,
                                                   const float* __restrict__ gw,
                                                   const float* __restrict__ gb,
                                                   const float* __restrict__ rw,
                                                   const float* __restrict__ rb,
                                                   int* __restrict__ idxo,
                                                   float* __restrict__ sco,
                                                   __bf16* __restrict__ Xb) {
  __shared__ float gws[512 * 17];   // 34816 B
  __shared__ float rws[512];        //  2048 B
  int tid = threadIdx.x;
  int w = tid >> 6, lane = tid & 63;
  int n = blockIdx.x * 4 + w;
  const float* xr = x + (size_t)n * DMODEL;
  __bf16* xbr = Xb + (size_t)n * DMODEL;

  float acc[17];
  #pragma unroll
  for (int j = 0; j < 17; j++) acc[j] = 0.f;

  for (int c = 0; c < 2; c++) {
    int c0 = c * 512;
    __syncthreads();   // protect previous chunk's reads before overwrite
    for (int i = tid; i < 512 * 16; i += 256)
      gws[(i >> 4) * 17 + (i & 15)] = gw[c0 * 16 + i];
    for (int i = tid; i < 512; i += 256)
      rws[i] = rw[c0 + i];
    __syncthreads();

    float xv[8];
    #pragma unroll
    for (int u = 0; u < 8; u++) xv[u] = xr[c0 + u * 64 + lane];
    #pragma unroll
    for (int u = 0; u < 8; u++) xbr[c0 + u * 64 + lane] = (__bf16)xv[u];
    #pragma unroll
    for (int u = 0; u < 8; u++) {
      int dl = u * 64 + lane;
      const float* g = &gws[dl * 17];
      #pragma unroll
      for (int j = 0; j < 16; j++) acc[j] += xv[u] * g[j];
      acc[16] += xv[u] * rws[dl];
    }
  }

  #pragma unroll
  for (int o = 1; o < 64; o <<= 1) {
    #pragma unroll
    for (int j = 0; j < 17; j++) acc[j] += __shfl_xor(acc[j], o);
  }
  if (lane == 0) {
    float rv = acc[16] + rb[0];
    bool g1 = rv > 0.f;
    float c[8];
    #pragma unroll
    for (int j = 0; j < 8; j++)
      c[j] = (g1 ? acc[j] + gb[j] : acc[8 + j] + gb[8 + j]);
    int i1 = 0; float v1 = c[0];
    #pragma unroll
    for (int j = 1; j < 8; j++) { if (c[j] > v1) { v1 = c[j]; i1 = j; } }
    int i2 = -1; float v2 = -3.4e38f;
    #pragma unroll
    for (int j = 0; j < 8; j++) { if (j != i1 && c[j] > v2) { v2 = c[j]; i2 = j; } }
    float e2 = expf(v2 - v1);
    float den = 1.f + e2;
    int base = g1 ? 0 : 8;
    idxo[2 * n] = base + i1; idxo[2 * n + 1] = base + i2;
    sco[2 * n] = 1.f / den;  sco[2 * n + 1] = e2 / den;
  }
}

// ------------- scan: t-ordered per-expert ranks, rowlists, offsets -------------
__global__ __launch_bounds__(1024) void scan_kernel(const int* __restrict__ idx,
                                                    float* __restrict__ sco,
                                                    int* __restrict__ rowlist,
                                                    int* __restrict__ cnt,
                                                    int* __restrict__ off) {
  __shared__ int hist[16 * 1024];   // 64 KB
  int tid = threadIdx.x;
  #pragma unroll
  for (int e = 0; e < 16; e++) hist[e * 1024 + tid] = 0;
  __syncthreads();
  int base = tid * 32;
  for (int i = 0; i < 32; i++) {
    int e = idx[base + i];
    hist[e * 1024 + tid]++;
  }
  __syncthreads();
  int w = tid >> 6, lane = tid & 63;
  {
    int e = w;  // 16 waves == 16 experts
    int running = 0;
    for (int cch = 0; cch < 16; cch++) {
      int v = hist[e * 1024 + cch * 64 + lane];
      int orig = v;
      #pragma unroll
      for (int o = 1; o < 64; o <<= 1) {
        int nv = __shfl_up(v, o);
        if (lane >= o) v += nv;
      }
      hist[e * 1024 + cch * 64 + lane] = running + v - orig;  // exclusive base
      running += __shfl(v, 63);
    }
    if (lane == 0) cnt[e] = running;   // raw count
  }
  __syncthreads();
  if (tid == 0) {
    int o = 0;
    for (int e = 0; e < 16; e++) {
      int c = cnt[e]; if (c > CAP) c = CAP;
      off[e] = o; cnt[e] = c; o += c;
    }
  }
  __syncthreads();
  for (int i = 0; i < 32; i++) {
    int t = base + i;
    int e = idx[t];
    int r = hist[e * 1024 + tid]++;
    if (r < CAP) rowlist[e * CAP + r] = t;
    else sco[t] = 0.f;   // dropped slot contributes zero
  }
}

// ------- grouped GEMM: 256x256x64 tile, 8 waves, prefetch double-buffer -------
#define GBM 256
#define GBN 256
#define GBK 64
#define NKT (DMODEL / GBK)   // 16 K-steps

__global__ __launch_bounds__(512) void moe_gemm(const __bf16* __restrict__ A,
                                                const __bf16* __restrict__ Bt,
                                                const float* __restrict__ bias,
                                                __bf16* __restrict__ out,
                                                const int* __restrict__ rowlist,
                                                const int* __restrict__ cnt,
                                                const int* __restrict__ off,
                                                int mode) {
  __shared__ char lds[131072];   // A: 2 x 32KB, B: 2 x 32KB
  // XCD-aware bijective swizzle on (expert, mtile): nwg=256, 256%8==0
  int bx = blockIdx.x;
  int em = (bx & 7) * 32 + (bx >> 3);
  int e  = em >> 4;
  int m0 = (em & 15) * GBM;
  int ce = cnt[e];
  if (m0 >= ce) return;
  int n0 = blockIdx.y * GBN;
  int oe = off[e];
  int tid = threadIdx.x;

  // staging source pointers: 4 A-granules + 4 B-granules (16B each) per thread
  const __bf16* aP[4];
  const __bf16* bP[4];
  #pragma unroll
  for (int j = 0; j < 4; j++) {
    int lin = j * 512 + tid;
    int r = lin >> 3;          // 0..255
    int g = lin & 7;           // 16B granule within 64-col row
    int rr = m0 + r; if (rr > ce - 1) rr = ce - 1;
    size_t arow;
    if (mode == 0) arow = (size_t)(rowlist[e * CAP + rr] >> 1);  // token id
    else           arow = (size_t)(oe + rr);                     // h row
    aP[j] = A + arow * DMODEL + g * 8;
    bP[j] = Bt + (size_t)e * DMODEL * DMODEL + (size_t)(n0 + r) * DMODEL + g * 8;
  }

  int w = tid >> 6, lane = tid & 63;
  int wr = (w >> 2) * 128;   // wave row: 2 M-groups of 128
  int wc = (w & 3) * 64;     // wave col: 4 N-groups of 64
  int fr = lane & 15, fg = lane >> 4;

  f32x4 acc[8][4];
  #pragma unroll
  for (int mi = 0; mi < 8; mi++)
    #pragma unroll
    for (int ni = 0; ni < 4; ni++)
      #pragma unroll
      for (int l = 0; l < 4; l++) acc[mi][ni][l] = 0.f;

  // prologue: stage tile 0 into buffer 0
  #pragma unroll
  for (int j = 0; j < 4; j++) {
    gl_lds16(aP[j], lds + (size_t)(j * 512 + tid) * 16);
    gl_lds16(bP[j], lds + 65536 + (size_t)(j * 512 + tid) * 16);
  }
  __syncthreads();

  int cur = 0;
  for (int t = 0; t < NKT; t++) {
    // prefetch next K-tile into the other buffer (overlaps MFMA below)
    if (t < NKT - 1) {
      int k0 = (t + 1) * GBK;
      char* Ad = lds + (cur ^ 1) * 32768;
      char* Bd = lds + 65536 + (cur ^ 1) * 32768;
      #pragma unroll
      for (int j = 0; j < 4; j++) {
        gl_lds16(aP[j] + k0, Ad + (size_t)(j * 512 + tid) * 16);
        gl_lds16(bP[j] + k0, Bd + (size_t)(j * 512 + tid) * 16);
      }
    }
    // compute current buffer
    char* As = lds + cur * 32768;
    char* Bs = lds + 65536 + cur * 32768;
    #pragma unroll
    for (int kk = 0; kk < 2; kk++) {
      bf16x8 af[8], bfr[4];
      #pragma unroll
      for (int mi = 0; mi < 8; mi++)
        af[mi] = *(const bf16x8*)(As + (size_t)(wr + mi * 16 + fr) * 128 + kk * 64 + fg * 16);
      #pragma unroll
      for (int ni = 0; ni < 4; ni++)
        bfr[ni] = *(const bf16x8*)(Bs + (size_t)(wc + ni * 16 + fr) * 128 + kk * 64 + fg * 16);
      #pragma unroll
      for (int mi = 0; mi < 8; mi++)
        #pragma unroll
        for (int ni = 0; ni < 4; ni++)
          acc[mi][ni] = __builtin_amdgcn_mfma_f32_16x16x32_bf16(af[mi], bfr[ni], acc[mi][ni], 0, 0, 0);
    }
    __syncthreads();   // drains this wave's vmcnt (prefetch) + all waves' LDS reads
    cur ^= 1;
  }

  float bcol[4];
  #pragma unroll
  for (int ni = 0; ni < 4; ni++)
    bcol[ni] = bias[(size_t)e * DMODEL + n0 + wc + ni * 16 + fr];
  #pragma unroll
  for (int mi = 0; mi < 8; mi++) {
    #pragma unroll
    for (int r = 0; r < 4; r++) {
      int grow = m0 + wr + mi * 16 + fg * 4 + r;
      if (grow >= ce) continue;
      size_t orow = (mode == 0) ? (size_t)(oe + grow)
                                : (size_t)rowlist[e * CAP + grow];
      __bf16* op = out + orow * DMODEL + n0 + wc + fr;
      #pragma unroll
      for (int ni = 0; ni < 4; ni++) {
        float v = acc[mi][ni][r] + bcol[ni];
        if (mode == 0) v = fmaxf(v, 0.f);
        op[ni * 16] = (__bf16)v;
      }
    }
  }
}

// ---------------- combine: out[n] = s0*y[2n] + s1*y[2n+1] ----------------
__global__ __launch_bounds__(256) void combine_kernel(const __bf16* __restrict__ y,
                                                      const float* __restrict__ sco,
                                                      float* __restrict__ out) {
  int n = blockIdx.x;
  int d = threadIdx.x * 4;
  float s0 = sco[2 * n], s1 = sco[2 * n + 1];
  ushort4 a = *(const ushort4*)((const unsigned short*)(y + (size_t)(2 * n) * DMODEL + d));
  ushort4 b = *(const ushort4*)((const unsigned short*)(y + (size_t)(2 * n + 1) * DMODEL + d));
  float4 o;
  o.x = s0 * bfbits2f(a.x) + s1 * bfbits2f(b.x);
  o.y = s0 * bfbits2f(a.y) + s1 * bfbits2f(b.y);
  o.z = s0 * bfbits2f(a.z) + s1 * bfbits2f(b.z);
  o.w = s0 * bfbits2f(a.w) + s1 * bfbits2f(b.w);
  *(float4*)(out + (size_t)n * DMODEL + d) = o;
}

extern "C" void kernel_launch(void* const* d_in, const int* in_sizes, int n_in,
                              void* d_out, int out_size, void* d_ws, size_t ws_size,
                              hipStream_t stream) {
  const float* moe = (const float*)d_in[0];
  const float* gw  = (const float*)d_in[1];
  const float* gb  = (const float*)d_in[2];
  const float* rw  = (const float*)d_in[3];
  const float* rb  = (const float*)d_in[4];
  const float* W1  = (const float*)d_in[5];
  const float* b1  = (const float*)d_in[6];
  const float* W2  = (const float*)d_in[7];
  const float* b2  = (const float*)d_in[8];
  float* out = (float*)d_out;

  char* p = (char*)d_ws;
  __bf16* Xb   = (__bf16*)p; p += (size_t)N_TOK * DMODEL * 2;
  __bf16* W1bt = (__bf16*)p; p += (size_t)EXP * DMODEL * DMODEL * 2;
  __bf16* W2bt = (__bf16*)p; p += (size_t)EXP * DMODEL * DMODEL * 2;
  __bf16* hbuf = (__bf16*)p; p += (size_t)TT * DMODEL * 2;
  __bf16* ybuf = (__bf16*)p; p += (size_t)TT * DMODEL * 2;
  int*   idxb   = (int*)p;   p += (size_t)TT * 4;
  float* scoreb = (float*)p; p += (size_t)TT * 4;
  int*   rowlist = (int*)p;  p += (size_t)EXP * CAP * 4;
  int*   cntb    = (int*)p;  p += 64;
  int*   offb    = (int*)p;  p += 64;

  convw_kernel<<<dim3(8192), dim3(256), 0, stream>>>(W1, W2, W1bt, W2bt);
  gate_kernel<<<dim3(4096), dim3(256), 0, stream>>>(moe, gw, gb, rw, rb, idxb, scoreb, Xb);
  scan_kernel<<<dim3(1), dim3(1024), 0, stream>>>(idxb, scoreb, rowlist, cntb, offb);
  moe_gemm<<<dim3(256, 4), dim3(512), 0, stream>>>(Xb, W1bt, b1, hbuf, rowlist, cntb, offb, 0);
  moe_gemm<<<dim3(256, 4), dim3(512), 0, stream>>>(hbuf, W2bt, b2, ybuf, rowlist, cntb, offb, 1);
  combine_kernel<<<dim3(16384), dim3(256), 0, stream>>>(ybuf, scoreb, out);
}

// Round 4
// 410.966 us; speedup vs baseline: 1.6314x; 1.0430x over previous
//
#include <hip/hip_runtime.h>
#include <hip/hip_bf16.h>
#include <stdint.h>

#define N_TOK 16384
#define DMODEL 1024
#define EXP 16
#define CAP 4096
#define TT 32768          // N_TOK * K (K=2)

typedef __bf16 bf16x8 __attribute__((ext_vector_type(8)));
typedef __bf16 bf16x4 __attribute__((ext_vector_type(4)));
typedef float  f32x4  __attribute__((ext_vector_type(4)));

__device__ __forceinline__ void gl_lds16(const void* g, void* s) {
  __builtin_amdgcn_global_load_lds(
      (__attribute__((address_space(1))) void*)(void*)g,
      (__attribute__((address_space(3))) void*)s, 16, 0, 0);
}

__device__ __forceinline__ float bfbits2f(unsigned short u) {
  return __uint_as_float(((unsigned)u) << 16);
}

#define FENCE asm volatile("" ::: "memory")
#define BAR() do { FENCE; __builtin_amdgcn_s_barrier(); FENCE; } while (0)

// ------------- transpose + convert W1/W2 to bf16 [e][n][k] -------------
__global__ __launch_bounds__(256) void convw_kernel(const float* __restrict__ W1,
                                                    const float* __restrict__ W2,
                                                    __bf16* __restrict__ W1bt,
                                                    __bf16* __restrict__ W2bt) {
  __shared__ float tile[64][65];
  int b = blockIdx.x;
  int tx = b & 15;           // col-tile (k dim of source)
  int ty = (b >> 4) & 15;    // row-tile
  int e  = (b >> 8) & 15;
  int which = (b >> 12) & 1;
  const float* src = (which ? W2 : W1) + (size_t)e * DMODEL * DMODEL;
  __bf16*      dst = (which ? W2bt : W1bt) + (size_t)e * DMODEL * DMODEL;
  int t = threadIdx.x;
  int r = t >> 2;             // 0..63
  int cs = (t & 3) * 16;      // 0,16,32,48
  int r0 = ty * 64, c0 = tx * 64;
  #pragma unroll
  for (int i = 0; i < 16; i += 4) {
    float4 v = *(const float4*)(src + (size_t)(r0 + r) * DMODEL + c0 + cs + i);
    tile[r][cs + i + 0] = v.x; tile[r][cs + i + 1] = v.y;
    tile[r][cs + i + 2] = v.z; tile[r][cs + i + 3] = v.w;
  }
  __syncthreads();
  bf16x8 o1, o2;
  #pragma unroll
  for (int i = 0; i < 8; i++) o1[i] = (__bf16)tile[cs + i][r];
  #pragma unroll
  for (int i = 0; i < 8; i++) o2[i] = (__bf16)tile[cs + 8 + i][r];
  *(bf16x8*)(dst + (size_t)(c0 + r) * DMODEL + r0 + cs)     = o1;
  *(bf16x8*)(dst + (size_t)(c0 + r) * DMODEL + r0 + cs + 8) = o2;
}

// ------- gate: logits via LDS-staged gw (fp32), fused X->bf16 -------
__global__ __launch_bounds__(256) void gate_kernel(const float* __restrict__ x,
                                                   const float* __restrict__ gw,
                                                   const float* __restrict__ gb,
                                                   const float* __restrict__ rw,
                                                   const float* __restrict__ rb,
                                                   int* __restrict__ idxo,
                                                   float* __restrict__ sco,
                                                   __bf16* __restrict__ Xb) {
  __shared__ float gws[512 * 17];   // 34816 B
  __shared__ float rws[512];        //  2048 B
  int tid = threadIdx.x;
  int w = tid >> 6, lane = tid & 63;
  int n = blockIdx.x * 4 + w;
  const float* xr = x + (size_t)n * DMODEL;
  __bf16* xbr = Xb + (size_t)n * DMODEL;

  float acc[17];
  #pragma unroll
  for (int j = 0; j < 17; j++) acc[j] = 0.f;

  for (int c = 0; c < 2; c++) {
    int c0 = c * 512;
    __syncthreads();   // protect previous chunk's reads before overwrite
    for (int i = tid; i < 512 * 16; i += 256)
      gws[(i >> 4) * 17 + (i & 15)] = gw[c0 * 16 + i];
    for (int i = tid; i < 512; i += 256)
      rws[i] = rw[c0 + i];
    __syncthreads();

    float xv[8];
    #pragma unroll
    for (int u = 0; u < 8; u++) xv[u] = xr[c0 + u * 64 + lane];
    #pragma unroll
    for (int u = 0; u < 8; u++) xbr[c0 + u * 64 + lane] = (__bf16)xv[u];
    #pragma unroll
    for (int u = 0; u < 8; u++) {
      int dl = u * 64 + lane;
      const float* g = &gws[dl * 17];
      #pragma unroll
      for (int j = 0; j < 16; j++) acc[j] += xv[u] * g[j];
      acc[16] += xv[u] * rws[dl];
    }
  }

  #pragma unroll
  for (int o = 1; o < 64; o <<= 1) {
    #pragma unroll
    for (int j = 0; j < 17; j++) acc[j] += __shfl_xor(acc[j], o);
  }
  if (lane == 0) {
    float rv = acc[16] + rb[0];
    bool g1 = rv > 0.f;
    float c[8];
    #pragma unroll
    for (int j = 0; j < 8; j++)
      c[j] = (g1 ? acc[j] + gb[j] : acc[8 + j] + gb[8 + j]);
    int i1 = 0; float v1 = c[0];
    #pragma unroll
    for (int j = 1; j < 8; j++) { if (c[j] > v1) { v1 = c[j]; i1 = j; } }
    int i2 = -1; float v2 = -3.4e38f;
    #pragma unroll
    for (int j = 0; j < 8; j++) { if (j != i1 && c[j] > v2) { v2 = c[j]; i2 = j; } }
    float e2 = expf(v2 - v1);
    float den = 1.f + e2;
    int base = g1 ? 0 : 8;
    idxo[2 * n] = base + i1; idxo[2 * n + 1] = base + i2;
    sco[2 * n] = 1.f / den;  sco[2 * n + 1] = e2 / den;
  }
}

// ------------- scan: t-ordered per-expert ranks, rowlists, offsets -------------
__global__ __launch_bounds__(1024) void scan_kernel(const int* __restrict__ idx,
                                                    float* __restrict__ sco,
                                                    int* __restrict__ rowlist,
                                                    int* __restrict__ cnt,
                                                    int* __restrict__ off) {
  __shared__ int hist[16 * 1024];   // 64 KB
  int tid = threadIdx.x;
  #pragma unroll
  for (int e = 0; e < 16; e++) hist[e * 1024 + tid] = 0;
  __syncthreads();
  int base = tid * 32;
  for (int i = 0; i < 32; i++) {
    int e = idx[base + i];
    hist[e * 1024 + tid]++;
  }
  __syncthreads();
  int w = tid >> 6, lane = tid & 63;
  {
    int e = w;  // 16 waves == 16 experts
    int running = 0;
    for (int cch = 0; cch < 16; cch++) {
      int v = hist[e * 1024 + cch * 64 + lane];
      int orig = v;
      #pragma unroll
      for (int o = 1; o < 64; o <<= 1) {
        int nv = __shfl_up(v, o);
        if (lane >= o) v += nv;
      }
      hist[e * 1024 + cch * 64 + lane] = running + v - orig;  // exclusive base
      running += __shfl(v, 63);
    }
    if (lane == 0) cnt[e] = running;   // raw count
  }
  __syncthreads();
  if (tid == 0) {
    int o = 0;
    for (int e = 0; e < 16; e++) {
      int c = cnt[e]; if (c > CAP) c = CAP;
      off[e] = o; cnt[e] = c; o += c;
    }
  }
  __syncthreads();
  for (int i = 0; i < 32; i++) {
    int t = base + i;
    int e = idx[t];
    int r = hist[e * 1024 + tid]++;
    if (r < CAP) rowlist[e * CAP + r] = t;
    else sco[t] = 0.f;   // dropped slot contributes zero
  }
}

// ------- grouped GEMM: 256x256x64, 8 waves, 8-phase counted-vmcnt schedule -------
// LDS: A = [buf][half][128 rows][8 granules of 16B], B same at +65536.
// Granule swizzle (T2): LDS slot (row,g) holds matrix granule g^(row&7);
// readers XOR, writers pre-swizzle the GLOBAL source (gl_lds dest stays linear).
// Phases per K-tile t (buf b=t&1):
//  P1 read A(mi0-3)+B(ni0-1); stage A0(t+1)->buf b^1   | mfma acc[0-3][0-1]
//  P2 read B(ni2-3);          stage A1(t+1)->buf b^1   | mfma acc[0-3][2-3]
//  P3 read A(mi4-7);          stage B0(t+2)->buf b     | mfma acc[4-7][2-3]
//  P4 (no reads);             stage B1(t+2)->buf b     | mfma acc[4-7][0-1]
//  end-P4: s_waitcnt vmcnt(4) (newest 4 = B(t+2)) -> next tile's data landed.
#define GBM 256
#define GBN 256
#define GBK 64
#define NKT (DMODEL / GBK)   // 16 K-steps

__global__ __launch_bounds__(512) void moe_gemm(const __bf16* __restrict__ A,
                                                const __bf16* __restrict__ Bt,
                                                const float* __restrict__ bias,
                                                __bf16* __restrict__ out,
                                                const int* __restrict__ rowlist,
                                                const int* __restrict__ cnt,
                                                const int* __restrict__ off,
                                                int mode) {
  __shared__ char lds[131072];
  int bx = blockIdx.x;
  int em = (bx & 7) * 32 + (bx >> 3);   // XCD-aware bijective swizzle (256%8==0)
  int e  = em >> 4;
  int m0 = (em & 15) * GBM;
  int ce = cnt[e];
  if (m0 >= ce) return;
  int n0 = blockIdx.y * GBN;
  int oe = off[e];
  int tid = threadIdx.x;

  // staging source pointers [half][j], granule pre-swizzled
  const __bf16* aP[2][2];
  const __bf16* bP[2][2];
  #pragma unroll
  for (int h = 0; h < 2; h++)
    #pragma unroll
    for (int j = 0; j < 2; j++) {
      int lin = j * 512 + tid;
      int srow = lin >> 3;
      int gsrc = (lin & 7) ^ (srow & 7);
      int rr = m0 + h * 128 + srow; if (rr > ce - 1) rr = ce - 1;
      size_t arow;
      if (mode == 0) arow = (size_t)(rowlist[e * CAP + rr] >> 1);  // token id
      else           arow = (size_t)(oe + rr);                     // h row
      aP[h][j] = A + arow * DMODEL + gsrc * 8;
      bP[h][j] = Bt + (size_t)e * DMODEL * DMODEL + (size_t)(n0 + h * 128 + srow) * DMODEL + gsrc * 8;
    }

  int w = tid >> 6, lane = tid & 63;
  int ah = w >> 2;              // A half (wave rows = ah*128 .. +127)
  int bh = (w & 3) >> 1;        // B half
  int bl = (w & 1) * 64;        // B local row base within half
  int fr = lane & 15, fg = lane >> 4;

  int aRd = ah * 16384 + fr * 128;                 // + buf + mi*2048 + gk
  int bRd = 65536 + bh * 16384 + (bl + fr) * 128;  // + buf + ni*2048 + gk
  int gk0 = ((fg)     ^ (fr & 7)) * 16;
  int gk1 = ((4 | fg) ^ (fr & 7)) * 16;

  f32x4 acc[8][4];
  #pragma unroll
  for (int mi = 0; mi < 8; mi++)
    #pragma unroll
    for (int ni = 0; ni < 4; ni++)
      #pragma unroll
      for (int l = 0; l < 4; l++) acc[mi][ni][l] = 0.f;

  auto stA = [&](int s, int h) {
    char* dst = lds + (s & 1) * 32768 + h * 16384;
    gl_lds16(aP[h][0] + s * 64, dst + (size_t)tid * 16);
    gl_lds16(aP[h][1] + s * 64, dst + (size_t)(512 + tid) * 16);
  };
  auto stB = [&](int s, int h) {
    char* dst = lds + 65536 + (s & 1) * 32768 + h * 16384;
    gl_lds16(bP[h][0] + s * 64, dst + (size_t)tid * 16);
    gl_lds16(bP[h][1] + s * 64, dst + (size_t)(512 + tid) * 16);
  };

  // prologue: tiles 0 and 1 fully staged
  stA(0, 0); stA(0, 1); stB(0, 0); stB(0, 1);
  stA(1, 0); stA(1, 1); stB(1, 0); stB(1, 1);
  asm volatile("s_waitcnt vmcnt(8)" ::: "memory");   // tile0 landed (tile1's 8 in flight)
  BAR();

  bf16x8 afA[4][2], bq0[2][2], bq1[2][2];
  for (int t = 0; t < NKT; ++t) {
    const char* Ab = lds + (t & 1) * 32768 + aRd;
    const char* Bb = lds + (t & 1) * 32768 + bRd;

    // ---------------- P1 ----------------
    #pragma unroll
    for (int mi = 0; mi < 4; mi++) {
      afA[mi][0] = *(const bf16x8*)(Ab + mi * 2048 + gk0);
      afA[mi][1] = *(const bf16x8*)(Ab + mi * 2048 + gk1);
    }
    #pragma unroll
    for (int ni = 0; ni < 2; ni++) {
      bq0[ni][0] = *(const bf16x8*)(Bb + ni * 2048 + gk0);
      bq0[ni][1] = *(const bf16x8*)(Bb + ni * 2048 + gk1);
    }
    if (t >= 1 && t <= 14) stA(t + 1, 0);
    BAR();
    __builtin_amdgcn_s_setprio(1);
    #pragma unroll
    for (int kk = 0; kk < 2; kk++)
      #pragma unroll
      for (int mi = 0; mi < 4; mi++)
        #pragma unroll
        for (int ni = 0; ni < 2; ni++)
          acc[mi][ni] = __builtin_amdgcn_mfma_f32_16x16x32_bf16(afA[mi][kk], bq0[ni][kk], acc[mi][ni], 0, 0, 0);
    __builtin_amdgcn_s_setprio(0);
    BAR();

    // ---------------- P2 ----------------
    #pragma unroll
    for (int ni = 0; ni < 2; ni++) {
      bq1[ni][0] = *(const bf16x8*)(Bb + (2 + ni) * 2048 + gk0);
      bq1[ni][1] = *(const bf16x8*)(Bb + (2 + ni) * 2048 + gk1);
    }
    if (t >= 1 && t <= 14) stA(t + 1, 1);
    BAR();
    __builtin_amdgcn_s_setprio(1);
    #pragma unroll
    for (int kk = 0; kk < 2; kk++)
      #pragma unroll
      for (int mi = 0; mi < 4; mi++)
        #pragma unroll
        for (int ni = 0; ni < 2; ni++)
          acc[mi][2 + ni] = __builtin_amdgcn_mfma_f32_16x16x32_bf16(afA[mi][kk], bq1[ni][kk], acc[mi][2 + ni], 0, 0, 0);
    __builtin_amdgcn_s_setprio(0);
    BAR();

    // ---------------- P3 ----------------
    #pragma unroll
    for (int mi = 0; mi < 4; mi++) {
      afA[mi][0] = *(const bf16x8*)(Ab + (4 + mi) * 2048 + gk0);
      afA[mi][1] = *(const bf16x8*)(Ab + (4 + mi) * 2048 + gk1);
    }
    if (t <= 13) stB(t + 2, 0);
    BAR();
    __builtin_amdgcn_s_setprio(1);
    #pragma unroll
    for (int kk = 0; kk < 2; kk++)
      #pragma unroll
      for (int mi = 0; mi < 4; mi++)
        #pragma unroll
        for (int ni = 0; ni < 2; ni++)
          acc[4 + mi][2 + ni] = __builtin_amdgcn_mfma_f32_16x16x32_bf16(afA[mi][kk], bq1[ni][kk], acc[4 + mi][2 + ni], 0, 0, 0);
    __builtin_amdgcn_s_setprio(0);
    BAR();

    // ---------------- P4 ----------------
    if (t <= 13) stB(t + 2, 1);
    BAR();
    __builtin_amdgcn_s_setprio(1);
    #pragma unroll
    for (int kk = 0; kk < 2; kk++)
      #pragma unroll
      for (int mi = 0; mi < 4; mi++)
        #pragma unroll
        for (int ni = 0; ni < 2; ni++)
          acc[4 + mi][ni] = __builtin_amdgcn_mfma_f32_16x16x32_bf16(afA[mi][kk], bq0[ni][kk], acc[4 + mi][ni], 0, 0, 0);
    __builtin_amdgcn_s_setprio(0);
    if (t <= 13)      asm volatile("s_waitcnt vmcnt(4)" ::: "memory");
    else if (t == 14) asm volatile("s_waitcnt vmcnt(0)" ::: "memory");
    BAR();
  }

  int wr = ah * 128, wc = (w & 3) * 64;
  float bcol[4];
  #pragma unroll
  for (int ni = 0; ni < 4; ni++)
    bcol[ni] = bias[(size_t)e * DMODEL + n0 + wc + ni * 16 + fr];
  #pragma unroll
  for (int mi = 0; mi < 8; mi++) {
    #pragma unroll
    for (int r = 0; r < 4; r++) {
      int grow = m0 + wr + mi * 16 + fg * 4 + r;
      if (grow >= ce) continue;
      size_t orow = (mode == 0) ? (size_t)(oe + grow)
                                : (size_t)rowlist[e * CAP + grow];
      __bf16* op = out + orow * DMODEL + n0 + wc + fr;
      #pragma unroll
      for (int ni = 0; ni < 4; ni++) {
        float v = acc[mi][ni][r] + bcol[ni];
        if (mode == 0) v = fmaxf(v, 0.f);
        op[ni * 16] = (__bf16)v;
      }
    }
  }
}

// ---------------- combine: out[n] = s0*y[2n] + s1*y[2n+1] ----------------
__global__ __launch_bounds__(256) void combine_kernel(const __bf16* __restrict__ y,
                                                      const float* __restrict__ sco,
                                                      float* __restrict__ out) {
  int n = blockIdx.x;
  int d = threadIdx.x * 4;
  float s0 = sco[2 * n], s1 = sco[2 * n + 1];
  ushort4 a = *(const ushort4*)((const unsigned short*)(y + (size_t)(2 * n) * DMODEL + d));
  ushort4 b = *(const ushort4*)((const unsigned short*)(y + (size_t)(2 * n + 1) * DMODEL + d));
  float4 o;
  o.x = s0 * bfbits2f(a.x) + s1 * bfbits2f(b.x);
  o.y = s0 * bfbits2f(a.y) + s1 * bfbits2f(b.y);
  o.z = s0 * bfbits2f(a.z) + s1 * bfbits2f(b.z);
  o.w = s0 * bfbits2f(a.w) + s1 * bfbits2f(b.w);
  *(float4*)(out + (size_t)n * DMODEL + d) = o;
}

extern "C" void kernel_launch(void* const* d_in, const int* in_sizes, int n_in,
                              void* d_out, int out_size, void* d_ws, size_t ws_size,
                              hipStream_t stream) {
  const float* moe = (const float*)d_in[0];
  const float* gw  = (const float*)d_in[1];
  const float* gb  = (const float*)d_in[2];
  const float* rw  = (const float*)d_in[3];
  const float* rb  = (const float*)d_in[4];
  const float* W1  = (const float*)d_in[5];
  const float* b1  = (const float*)d_in[6];
  const float* W2  = (const float*)d_in[7];
  const float* b2  = (const float*)d_in[8];
  float* out = (float*)d_out;

  char* p = (char*)d_ws;
  __bf16* Xb   = (__bf16*)p; p += (size_t)N_TOK * DMODEL * 2;
  __bf16* W1bt = (__bf16*)p; p += (size_t)EXP * DMODEL * DMODEL * 2;
  __bf16* W2bt = (__bf16*)p; p += (size_t)EXP * DMODEL * DMODEL * 2;
  __bf16* hbuf = (__bf16*)p; p += (size_t)TT * DMODEL * 2;
  __bf16* ybuf = (__bf16*)p; p += (size_t)TT * DMODEL * 2;
  int*   idxb   = (int*)p;   p += (size_t)TT * 4;
  float* scoreb = (float*)p; p += (size_t)TT * 4;
  int*   rowlist = (int*)p;  p += (size_t)EXP * CAP * 4;
  int*   cntb    = (int*)p;  p += 64;
  int*   offb    = (int*)p;  p += 64;

  convw_kernel<<<dim3(8192), dim3(256), 0, stream>>>(W1, W2, W1bt, W2bt);
  gate_kernel<<<dim3(4096), dim3(256), 0, stream>>>(moe, gw, gb, rw, rb, idxb, scoreb, Xb);
  scan_kernel<<<dim3(1), dim3(1024), 0, stream>>>(idxb, scoreb, rowlist, cntb, offb);
  moe_gemm<<<dim3(256, 4), dim3(512), 0, stream>>>(Xb, W1bt, b1, hbuf, rowlist, cntb, offb, 0);
  moe_gemm<<<dim3(256, 4), dim3(512), 0, stream>>>(hbuf, W2bt, b2, ybuf, rowlist, cntb, offb, 1);
  combine_kernel<<<dim3(16384), dim3(256), 0, stream>>>(ybuf, scoreb, out);
}